// Round 10
// baseline (89.044 us; speedup 1.0000x reference)
//
#include <hip/hip_runtime.h>
#include <hip/hip_bf16.h>
#include <math.h>

#define B_ 128
#define C_ 8
#define T_ 128
#define K_ 20
#define S_ 128

#define SWZ(j) ((j) ^ ((((j) >> 5) & 7) << 2))
#define XSTR 420            // cc xp row stride; SWZ image of [0,392) fits (<420), injective
#define BTSTR 132           // bt row stride: %4==0, %32==4 -> 8 channel rows de-alias
#define TILEF 1536          // dtw tile [128][12]: x[t][c] cols 0-7, X2 col 8
#define SMEMF 7584          // cc: 8*420 + 4*8*132 = 7584 floats; dtw: 2*1536 = 3072

template <int CTRL, int RMASK>
__device__ __forceinline__ float dppf(float oldv, float v) {
    return __int_as_float(__builtin_amdgcn_update_dpp(
        __float_as_int(oldv), __float_as_int(v), CTRL, RMASK, 0xf, false));
}

// One CC step of 8 s-values with a compile-time circular 40-reg window:
// all window indices constant-folded -> pure register file, zero slide movs.
template <int BASE>
__device__ __forceinline__ void cstep(float (&wdw)[40], float (&acc)[32],
                                      const float* br, const float* xr,
                                      int s8, int lag0) {
    float4 b0 = *(const float4*)&br[s8];
    float4 b1 = *(const float4*)&br[s8 + 4];
    float bvv[8] = {b0.x, b0.y, b0.z, b0.w, b1.x, b1.y, b1.z, b1.w};
    #pragma unroll
    for (int uu = 0; uu < 8; ++uu) {
        #pragma unroll
        for (int jj = 0; jj < 32; ++jj)
            acc[jj] = fmaf(wdw[(BASE + uu + jj) % 40], bvv[uu], acc[jj]);
    }
    // Refill the 8 slots just consumed with lags s8+40..s8+47 (in-bounds: <392).
    float4 p0 = *(const float4*)&xr[SWZ(lag0 + s8 + 40)];
    float4 p1 = *(const float4*)&xr[SWZ(lag0 + s8 + 44)];
    wdw[(BASE + 0) % 40] = p0.x; wdw[(BASE + 1) % 40] = p0.y;
    wdw[(BASE + 2) % 40] = p0.z; wdw[(BASE + 3) % 40] = p0.w;
    wdw[(BASE + 4) % 40] = p1.x; wdw[(BASE + 5) % 40] = p1.y;
    wdw[(BASE + 6) % 40] = p1.z; wdw[(BASE + 7) % 40] = p1.w;
}

// 960 blocks x 256 threads, explicit 128-VGPR cap (16 waves/CU).
// u%3==0 -> DTW (4 waves, TWO pairs/wave, row-sweep min-plus scan).
// else   -> CC  (4 waves, ONE (b,k)/wave: 8 ch x 8 lanes x 32 lags).
__global__ __launch_bounds__(256, 4) void fused_kernel(const float* __restrict__ x,
                                                       const float* __restrict__ bary,
                                                       const float* __restrict__ top_dist,
                                                       const float* __restrict__ bottom_cc,
                                                       int* __restrict__ dtw_gt,
                                                       int* __restrict__ cc_fail) {
    __shared__ __align__(16) float smem[SMEMF];
    const float INF = __builtin_inff();
    int u = blockIdx.x;
    int tid = threadIdx.x;
    int w = tid >> 6;
    int lane = tid & 63;

    if (u % 3 == 0) {
        // ------------------------------ DTW ------------------------------
        int j  = u / 3;                  // 0..319
        int p0 = j * 8 + w * 2;          // wave's pairs p0, p0+1 (same b: p0 even)
        int b  = p0 / K_;
        int k0 = p0 - b * K_;
        int b_lo = (j * 8) / K_;
        int b_hi = (j * 8 + 7) / K_;
        float* tile0 = smem;
        float* tile1 = smem + TILEF;

        {   // stage x[b_lo] -> tile0, x[b_hi] -> tile1
            int c  = tid >> 5;
            int t0 = (tid & 31) * 4;
            float4 v0 = *(const float4*)(x + ((size_t)b_lo * C_ + c) * T_ + t0);
            float4 v1 = *(const float4*)(x + ((size_t)b_hi * C_ + c) * T_ + t0);
            tile0[(t0 + 0) * 12 + c] = v0.x;
            tile0[(t0 + 1) * 12 + c] = v0.y;
            tile0[(t0 + 2) * 12 + c] = v0.z;
            tile0[(t0 + 3) * 12 + c] = v0.w;
            tile1[(t0 + 0) * 12 + c] = v1.x;
            tile1[(t0 + 1) * 12 + c] = v1.y;
            tile1[(t0 + 2) * 12 + c] = v1.z;
            tile1[(t0 + 3) * 12 + c] = v1.w;
        }
        __syncthreads();
        {   // X2[t] -> col 8
            float* tt = (tid < T_) ? tile0 : tile1;
            int t = tid & (T_ - 1);
            const float* rp = tt + t * 12;
            float4 xa = *(const float4*)rp;
            float4 xh = *(const float4*)(rp + 4);
            float s = xa.x * xa.x;
            s = fmaf(xa.y, xa.y, s); s = fmaf(xa.z, xa.z, s); s = fmaf(xa.w, xa.w, s);
            s = fmaf(xh.x, xh.x, s); s = fmaf(xh.y, xh.y, s); s = fmaf(xh.z, xh.z, s);
            s = fmaf(xh.w, xh.w, s);
            tt[t * 12 + 8] = s;
        }
        __syncthreads();

        const float* tile = (b == b_lo) ? tile0 : tile1;

        float bvA0[8], bvA1[8], bvB0[8], bvB1[8], B2A0, B2A1, B2B0, B2B1;
        {
            const float4* bpA = (const float4*)(bary + ((size_t)k0 * S_ + 2 * lane) * C_);
            const float4* bpB = (const float4*)(bary + ((size_t)(k0 + 1) * S_ + 2 * lane) * C_);
            float4 qa0 = bpA[0], qa1 = bpA[1], qa2 = bpA[2], qa3 = bpA[3];
            float4 qb0 = bpB[0], qb1 = bpB[1], qb2 = bpB[2], qb3 = bpB[3];
            bvA0[0]=qa0.x; bvA0[1]=qa0.y; bvA0[2]=qa0.z; bvA0[3]=qa0.w;
            bvA0[4]=qa1.x; bvA0[5]=qa1.y; bvA0[6]=qa1.z; bvA0[7]=qa1.w;
            bvA1[0]=qa2.x; bvA1[1]=qa2.y; bvA1[2]=qa2.z; bvA1[3]=qa2.w;
            bvA1[4]=qa3.x; bvA1[5]=qa3.y; bvA1[6]=qa3.z; bvA1[7]=qa3.w;
            bvB0[0]=qb0.x; bvB0[1]=qb0.y; bvB0[2]=qb0.z; bvB0[3]=qb0.w;
            bvB0[4]=qb1.x; bvB0[5]=qb1.y; bvB0[6]=qb1.z; bvB0[7]=qb1.w;
            bvB1[0]=qb2.x; bvB1[1]=qb2.y; bvB1[2]=qb2.z; bvB1[3]=qb2.w;
            bvB1[4]=qb3.x; bvB1[5]=qb3.y; bvB1[6]=qb3.z; bvB1[7]=qb3.w;
            float sA0=0.f, sA1=0.f, sB0=0.f, sB1=0.f;
            #pragma unroll
            for (int ch = 0; ch < 8; ++ch) {
                sA0 = fmaf(bvA0[ch], bvA0[ch], sA0);
                sA1 = fmaf(bvA1[ch], bvA1[ch], sA1);
                sB0 = fmaf(bvB0[ch], bvB0[ch], sB0);
                sB1 = fmaf(bvB1[ch], bvB1[ch], sB1);
            }
            B2A0 = sA0; B2A1 = sA1; B2B0 = sB0; B2B1 = sB1;
            #pragma unroll
            for (int ch = 0; ch < 8; ++ch) {
                bvA0[ch] *= -2.f; bvA1[ch] *= -2.f;
                bvB0[ch] *= -2.f; bvB1[ch] *= -2.f;
            }
        }

        float nA0 = INF, nA1 = INF, nB0 = INF, nB1 = INF;
        float dfix = (lane == 0) ? 0.f : INF;   // virtual D[-1][-1]=0, row 0 only

        __builtin_amdgcn_s_setprio(1);
        float4 xa_n = *(const float4*)tile;
        float4 xh_n = *(const float4*)(tile + 4);
        float x2_n  = tile[8];

        #pragma unroll 1
        for (int t = 0; t < T_; ++t) {
            float4 xa = xa_n, xh = xh_n;
            float X2t = x2_n;
            const float* rpn = tile + ((t + 1) & (T_ - 1)) * 12;
            xa_n = *(const float4*)rpn;
            xh_n = *(const float4*)(rpn + 4);
            x2_n = rpn[8];

            float xv[8];
            xv[0]=xa.x; xv[1]=xa.y; xv[2]=xa.z; xv[3]=xa.w;
            xv[4]=xh.x; xv[5]=xh.y; xv[6]=xh.z; xv[7]=xh.w;
            // cost = X2+B2-2xb; no clamp to 0 (fp32 undershoot <=1e-4 -> log shift ~1e-5)
            float aA0 = X2t + B2A0, aA1 = X2t + B2A1;
            float aB0 = X2t + B2B0, aB1 = X2t + B2B1;
            #pragma unroll
            for (int ch = 0; ch < 8; ++ch) {
                aA0 = fmaf(bvA0[ch], xv[ch], aA0);
                aA1 = fmaf(bvA1[ch], xv[ch], aA1);
                aB0 = fmaf(bvB0[ch], xv[ch], aB0);
                aB1 = fmaf(bvB1[ch], xv[ch], aB1);
            }

            float diagA = dppf<0x138, 0xf>(INF, nA1);
            float diagB = dppf<0x138, 0xf>(INF, nB1);
            float mA0 = fminf(fminf(nA0, diagA), dfix);
            float mB0 = fminf(fminf(nB0, diagB), dfix);
            float mA1 = fminf(nA1, nA0);
            float mB1 = fminf(nB1, nB0);
            dfix = INF;
            float CA0 = aA0 + mA0, CA1 = aA1 + mA1;
            float CB0 = aB0 + mB0, CB1 = aB1 + mB1;
            float CA = fminf(CA1, CA0 + aA1);  float AA = aA0 + aA1;
            float CB = fminf(CB1, CB0 + aB1);  float AB = aB0 + aB1;

            float CiA, AiA, CiB, AiB;
            #define SCAN_STEP(CTRL, RMASK)                                          \
                CiA = dppf<CTRL, RMASK>(INF, CA); AiA = dppf<CTRL, RMASK>(0.f, AA); \
                CiB = dppf<CTRL, RMASK>(INF, CB); AiB = dppf<CTRL, RMASK>(0.f, AB); \
                CA = fminf(CA, CiA + AA); AA = AA + AiA;                            \
                CB = fminf(CB, CiB + AB); AB = AB + AiB;
            SCAN_STEP(0x111, 0xf)   // row_shr:1
            SCAN_STEP(0x112, 0xf)   // row_shr:2
            SCAN_STEP(0x114, 0xf)   // row_shr:4
            SCAN_STEP(0x118, 0xf)   // row_shr:8
            SCAN_STEP(0x142, 0xa)   // row_bcast15 -> rows 1,3
            SCAN_STEP(0x143, 0xc)   // row_bcast31 -> rows 2,3
            #undef SCAN_STEP

            float CpA = dppf<0x138, 0xf>(INF, CA);
            float CpB = dppf<0x138, 0xf>(INF, CB);
            nA0 = fminf(CA0, CpA + aA0);  nA1 = CA;
            nB0 = fminf(CB0, CpB + aB0);  nB1 = CB;
        }
        __builtin_amdgcn_s_setprio(0);

        if (lane == 63) {
            dtw_gt[p0]     = (logf(nA1) > top_dist[k0])     ? 1 : 0;
            dtw_gt[p0 + 1] = (logf(nB1) > top_dist[k0 + 1]) ? 1 : 0;
        }
    } else {
        // ------------------------------ CC -------------------------------
        int cb = u - u / 3 - 1;          // 0..639
        int bb = cb / 5;                 // b
        int g5 = cb - bb * 5;
        int kk = g5 * 4 + w;             // wave's k, 0..19

        float* xp = smem;                              // [8][XSTR], swizzled
        float* bt = smem + 8 * XSTR + w * (8 * BTSTR); // per-wave [8][BTSTR]

        // Stage x[bb] (shared by all 4 waves): logical xp[c][j]=x[c][j-127], j<392.
        const float* xsrc = x + (size_t)bb * (C_ * T_);
        #pragma unroll
        for (int c = 0; c < 8; ++c) {
            for (int jj = tid; jj < 392; jj += 256) {
                int t = jj - (S_ - 1);
                float v = (t >= 0 && t < T_) ? xsrc[c * T_ + t] : 0.f;
                xp[c * XSTR + SWZ(jj)] = v;
            }
        }
        // Stage bt (per wave): lane covers s=2*lane, 2*lane+1; coalesced float4 in.
        {
            const float* bp = bary + ((size_t)kk * S_ + 2 * lane) * C_;
            float4 q0 = *(const float4*)bp,       q1 = *(const float4*)(bp + 4);
            float4 q2 = *(const float4*)(bp + 8), q3 = *(const float4*)(bp + 12);
            int s0 = 2 * lane;
            bt[0*BTSTR+s0]=q0.x; bt[1*BTSTR+s0]=q0.y; bt[2*BTSTR+s0]=q0.z; bt[3*BTSTR+s0]=q0.w;
            bt[4*BTSTR+s0]=q1.x; bt[5*BTSTR+s0]=q1.y; bt[6*BTSTR+s0]=q1.z; bt[7*BTSTR+s0]=q1.w;
            bt[0*BTSTR+s0+1]=q2.x; bt[1*BTSTR+s0+1]=q2.y; bt[2*BTSTR+s0+1]=q2.z; bt[3*BTSTR+s0+1]=q2.w;
            bt[4*BTSTR+s0+1]=q3.x; bt[5*BTSTR+s0+1]=q3.y; bt[6*BTSTR+s0+1]=q3.z; bt[7*BTSTR+s0+1]=q3.w;
        }
        __syncthreads();

        int g  = lane >> 3;              // channel 0..7
        int gl = lane & 7;
        int lag0 = gl << 5;              // 32 lags/lane
        const float* xr = xp + g * XSTR;
        const float* br = bt + g * BTSTR;

        float wdw[40];
        #pragma unroll
        for (int i = 0; i < 10; ++i) {
            float4 v = *(const float4*)&xr[SWZ(lag0 + 4 * i)];
            wdw[4*i+0] = v.x; wdw[4*i+1] = v.y; wdw[4*i+2] = v.z; wdw[4*i+3] = v.w;
        }
        float acc[32];
        #pragma unroll
        for (int jj = 0; jj < 32; ++jj) acc[jj] = 0.f;

        // 16 steps of 8 s-values: 3 full rotations of the 40-slot window + tail.
        #pragma unroll 1
        for (int blk = 0; blk < 3; ++blk) {
            int s8 = blk * 40;
            cstep<0 >(wdw, acc, br, xr, s8,      lag0);
            cstep<8 >(wdw, acc, br, xr, s8 + 8,  lag0);
            cstep<16>(wdw, acc, br, xr, s8 + 16, lag0);
            cstep<24>(wdw, acc, br, xr, s8 + 24, lag0);
            cstep<32>(wdw, acc, br, xr, s8 + 32, lag0);
        }
        cstep<0>(wdw, acc, br, xr, 120, lag0);

        if (gl == 7) acc[31] = -INF;     // lag 255 doesn't exist
        float m = acc[0];
        #pragma unroll
        for (int jj = 1; jj < 32; ++jj) m = fmaxf(m, acc[jj]);
        m = fmaxf(m, __shfl_xor(m, 1));
        m = fmaxf(m, __shfl_xor(m, 2));
        m = fmaxf(m, __shfl_xor(m, 4));

        bool fail = false;
        if (gl == 0) fail = (m <= bottom_cc[kk * C_ + g]);
        unsigned long long bal = __ballot(fail);
        if (lane == 0) cc_fail[bb * K_ + kk] = (bal != 0ULL) ? 1 : 0;
    }
}

__global__ void final_kernel(const int* __restrict__ preds,
                             const int* __restrict__ dtw_gt,
                             const int* __restrict__ cc_fail,
                             int* __restrict__ out) {
    int b = threadIdx.x;
    if (b < B_) {
        int dtw_all = 1, cc_all = 1;
        #pragma unroll
        for (int k = 0; k < K_; ++k) {
            dtw_all &= dtw_gt[b * K_ + k];
            cc_all &= cc_fail[b * K_ + k];
        }
        out[b] = (dtw_all | cc_all) ? K_ : preds[b];
    }
}

extern "C" void kernel_launch(void* const* d_in, const int* in_sizes, int n_in,
                              void* d_out, int out_size, void* d_ws, size_t ws_size,
                              hipStream_t stream) {
    const float* x         = (const float*)d_in[0];  // [B, C, T]
    const int*   preds     = (const int*)d_in[1];    // [B]
    const float* bary      = (const float*)d_in[2];  // [K, S, C]
    const float* top_dist  = (const float*)d_in[3];  // [K]
    const float* bottom_cc = (const float*)d_in[4];  // [K, C]
    int* out = (int*)d_out;                          // [B] int32

    int* dtw_gt  = (int*)d_ws;                // [B*K]
    int* cc_fail = dtw_gt + B_ * K_;          // [B*K]

    fused_kernel<<<960, 256, 0, stream>>>(x, bary, top_dist, bottom_cc, dtw_gt, cc_fail);
    final_kernel<<<1, 128, 0, stream>>>(preds, dtw_gt, cc_fail, out);
}

// Round 11
// 65.779 us; speedup vs baseline: 1.3537x; 1.3537x over previous
//
#include <hip/hip_runtime.h>
#include <hip/hip_bf16.h>
#include <math.h>

#define B_ 128
#define C_ 8
#define T_ 128
#define K_ 20
#define S_ 128

#define SWZ(j) ((j) ^ ((((j) >> 5) & 7) << 2))
#define XROW 388            // cc x row stride: %4==0 (float4), %32==4 (groups de-alias)
#define BTROW 132
#define XP_GUARD 16
#define BT_BASE (4 * XROW + XP_GUARD)   // 1568 floats
#define TILEF 1536          // dtw tile [128][12]: x[t][c] cols 0-7, X2 col 8

template <int CTRL, int RMASK>
__device__ __forceinline__ float dppf(float oldv, float v) {
    return __int_as_float(__builtin_amdgcn_update_dpp(
        __float_as_int(oldv), __float_as_int(v), CTRL, RMASK, 0xf, false));
}

// ---------------------------------------------------------------------------
// DTW: 320 blocks x 256. Wave = 2 pairs (p0=2*wid, p0+1; same b since 20 even),
// pair A in lanes 0-31, pair B in lanes 32-63, 4 DP columns per lane.
// Row-sweep min-plus scan; 5 scan steps SHARED by both pairs (group-local).
// ---------------------------------------------------------------------------
__global__ __launch_bounds__(256, 2) void dtw_kernel(const float* __restrict__ x,
                                                     const float* __restrict__ bary,
                                                     const float* __restrict__ top_dist,
                                                     int* __restrict__ dtw_gt) {
    __shared__ __align__(16) float smem[2 * TILEF];
    const float INF = __builtin_inff();
    int u = blockIdx.x;
    int tid = threadIdx.x;
    int w = tid >> 6;
    int lane = tid & 63;

    int wid = u * 4 + w;                 // 0..1279
    int p0  = 2 * wid;                   // wave's pairs p0, p0+1 (same b)
    int b   = p0 / K_;
    int k0  = p0 - b * K_;
    int b_lo = (8 * u) / K_;
    int b_hi = (8 * u + 7) / K_;         // block spans <= 2 b's
    float* tile0 = smem;
    float* tile1 = smem + TILEF;

    {   // stage x[b_lo] -> tile0, x[b_hi] -> tile1 (coalesced float4)
        int c  = tid >> 5;
        int t0 = (tid & 31) * 4;
        float4 v0 = *(const float4*)(x + ((size_t)b_lo * C_ + c) * T_ + t0);
        float4 v1 = *(const float4*)(x + ((size_t)b_hi * C_ + c) * T_ + t0);
        tile0[(t0 + 0) * 12 + c] = v0.x;
        tile0[(t0 + 1) * 12 + c] = v0.y;
        tile0[(t0 + 2) * 12 + c] = v0.z;
        tile0[(t0 + 3) * 12 + c] = v0.w;
        tile1[(t0 + 0) * 12 + c] = v1.x;
        tile1[(t0 + 1) * 12 + c] = v1.y;
        tile1[(t0 + 2) * 12 + c] = v1.z;
        tile1[(t0 + 3) * 12 + c] = v1.w;
    }
    __syncthreads();
    {   // X2[t] -> col 8
        float* tt = (tid < T_) ? tile0 : tile1;
        int t = tid & (T_ - 1);
        const float* rp = tt + t * 12;
        float4 xa = *(const float4*)rp;
        float4 xh = *(const float4*)(rp + 4);
        float s = xa.x * xa.x;
        s = fmaf(xa.y, xa.y, s); s = fmaf(xa.z, xa.z, s); s = fmaf(xa.w, xa.w, s);
        s = fmaf(xh.x, xh.x, s); s = fmaf(xh.y, xh.y, s); s = fmaf(xh.z, xh.z, s);
        s = fmaf(xh.w, xh.w, s);
        tt[t * 12 + 8] = s;
    }
    __syncthreads();

    const float* tile = (b == b_lo) ? tile0 : tile1;

    int g  = lane >> 5;                  // which pair (0=A lanes0-31, 1=B)
    int gl = lane & 31;                  // lane within pair group
    int kx = k0 + g;                     // this half-wave's class

    // Barycenter: 4 cols s=4*gl..4*gl+3 of class kx; -2*b and B2 in registers.
    float bv[4][8], B2s[4];
    {
        const float4* bp = (const float4*)(bary + ((size_t)kx * S_ + 4 * gl) * C_);
        #pragma unroll
        for (int r = 0; r < 4; ++r) {
            float4 q0 = bp[2 * r], q1 = bp[2 * r + 1];
            bv[r][0] = q0.x; bv[r][1] = q0.y; bv[r][2] = q0.z; bv[r][3] = q0.w;
            bv[r][4] = q1.x; bv[r][5] = q1.y; bv[r][6] = q1.z; bv[r][7] = q1.w;
            float s = 0.f;
            #pragma unroll
            for (int ch = 0; ch < 8; ++ch) s = fmaf(bv[r][ch], bv[r][ch], s);
            B2s[r] = s;
            #pragma unroll
            for (int ch = 0; ch < 8; ++ch) bv[r][ch] *= -2.f;
        }
    }

    bool isg0 = (gl == 0);                       // group-left-edge lanes (0, 32)
    float n0 = INF, n1 = INF, n2 = INF, n3 = INF;
    float dfix = isg0 ? 0.f : INF;               // virtual D[-1][-1]=0, row 0 only

    // Prefetch row 0 (uniform broadcast reads, conflict-free).
    float4 xa_n = *(const float4*)tile;
    float4 xh_n = *(const float4*)(tile + 4);
    float x2_n  = tile[8];

    #pragma unroll 2
    for (int t = 0; t < T_; ++t) {
        float4 xa = xa_n, xh = xh_n;
        float X2t = x2_n;
        const float* rpn = tile + ((t + 1) & (T_ - 1)) * 12;
        xa_n = *(const float4*)rpn;
        xh_n = *(const float4*)(rpn + 4);
        x2_n = rpn[8];

        float xv[8];
        xv[0]=xa.x; xv[1]=xa.y; xv[2]=xa.z; xv[3]=xa.w;
        xv[4]=xh.x; xv[5]=xh.y; xv[6]=xh.z; xv[7]=xh.w;
        // cost_i = X2[t] + B2[s_i] - 2 x.b  (no clamp: fp32 undershoot ~1e-4
        // on dist ~1e3 -> log shift ~1e-7, far below decision gaps)
        float a0 = X2t + B2s[0], a1 = X2t + B2s[1];
        float a2 = X2t + B2s[2], a3 = X2t + B2s[3];
        #pragma unroll
        for (int ch = 0; ch < 8; ++ch) {
            a0 = fmaf(bv[0][ch], xv[ch], a0);
            a1 = fmaf(bv[1][ch], xv[ch], a1);
            a2 = fmaf(bv[2][ch], xv[ch], a2);
            a3 = fmaf(bv[3][ch], xv[ch], a3);
        }

        // diag for col 0 = prev-lane's n3; kill 31->32 leak + lane0 edge.
        float dl = dppf<0x138, 0xf>(INF, n3);    // wave_shr:1
        float diag = isg0 ? INF : dl;
        float m0 = fminf(fminf(n0, diag), dfix);
        float m1 = fminf(n1, n0);
        float m2 = fminf(n2, n1);
        float m3 = fminf(n3, n2);
        dfix = INF;
        float C0 = a0 + m0, C1 = a1 + m1, C2 = a2 + m2, C3 = a3 + m3;
        // in-lane compose (cols 0->3), keeping prefixes for reconstruction
        float A01  = a0 + a1;
        float C01  = fminf(C1, C0 + a1);
        float A012 = A01 + a2;
        float C012 = fminf(C2, C01 + a2);
        float A    = A012 + a3;
        float C    = fminf(C3, C012 + a3);

        // 32-lane inclusive min-plus scan, SHARED by both pairs (group-local:
        // row_shr never crosses 16-rows; bcast15 rmask 0xa feeds rows 1,3 only).
        float Ci, Ai;
        #define SCAN_STEP(CTRL, RMASK)                                         \
            Ci = dppf<CTRL, RMASK>(INF, C); Ai = dppf<CTRL, RMASK>(0.f, A);    \
            C = fminf(C, Ci + A); A = A + Ai;
        SCAN_STEP(0x111, 0xf)   // row_shr:1
        SCAN_STEP(0x112, 0xf)   // row_shr:2
        SCAN_STEP(0x114, 0xf)   // row_shr:4
        SCAN_STEP(0x118, 0xf)   // row_shr:8
        SCAN_STEP(0x142, 0xa)   // row_bcast15 -> lanes 16-31 / 48-63
        #undef SCAN_STEP

        // exclusive value = inclusive of prev lane; kill 31->32 leak + edge.
        float Cpw = dppf<0x138, 0xf>(INF, C);
        float Cp  = isg0 ? INF : Cpw;
        n0 = fminf(C0,   Cp + a0);
        n1 = fminf(C01,  Cp + A01);
        n2 = fminf(C012, Cp + A012);
        n3 = C;                                  // inclusive = col 4*gl+3 value
    }

    if (gl == 31)                                // lanes 31 (A) and 63 (B)
        dtw_gt[p0 + g] = (logf(n3) > top_dist[kx]) ? 1 : 0;
}

// ---------------------------------------------------------------------------
// CC: 1280 blocks x 256. Block = (b, channel-half) sharing one x-tile; wave =
// one k: 4 ch x 16 lanes x 16 lags. Compile-time circular 20-slot window
// (BASE period 5) -> zero slide movs, 36 window/acc registers (no spill).
// ---------------------------------------------------------------------------
template <int BASE>
__device__ __forceinline__ void cstep4(float (&wdw)[20], float (&acc)[16],
                                       const float* br, const float* xr,
                                       int s4, int lag0) {
    float4 bq = *(const float4*)&br[s4];
    float bvv[4] = {bq.x, bq.y, bq.z, bq.w};
    #pragma unroll
    for (int uu = 0; uu < 4; ++uu) {
        #pragma unroll
        for (int jj = 0; jj < 16; ++jj)
            acc[jj] = fmaf(wdw[(BASE + uu + jj) % 20], bvv[uu], acc[jj]);
    }
    // refill the 4 consumed slots with lags s4+20..s4+23 (reads <= 387 < XROW)
    float4 p = *(const float4*)&xr[SWZ(lag0 + s4 + 20)];
    wdw[(BASE + 0) % 20] = p.x; wdw[(BASE + 1) % 20] = p.y;
    wdw[(BASE + 2) % 20] = p.z; wdw[(BASE + 3) % 20] = p.w;
}

__global__ __launch_bounds__(256, 4) void cc_kernel(const float* __restrict__ x,
                                                    const float* __restrict__ bary,
                                                    const float* __restrict__ bottom_cc,
                                                    int* __restrict__ cc_fail2) {
    __shared__ __align__(16) float smem[BT_BASE + 4 * 8 * BTROW];
    const float INF = __builtin_inff();
    int cb = blockIdx.x;                 // 0..1279
    int tid = threadIdx.x;
    int w = tid >> 6;
    int lane = tid & 63;

    int bh = cb / 5;                     // (b, half)
    int g5 = cb - bh * 5;
    int b  = bh >> 1;
    int h  = bh & 1;
    int kk = g5 * 4 + w;                 // wave's k
    int cbase = h * 4;

    float* xp = smem;                              // 4 x XROW (+guard), swizzled
    float* bt = smem + BT_BASE + w * (4 * BTROW);

    const float* xsrc = x + ((size_t)b * C_ + cbase) * T_;
    #pragma unroll
    for (int c = 0; c < 4; ++c) {
        for (int jj = tid; jj < XROW; jj += 256) {
            int t = jj - (S_ - 1);
            float v = (t >= 0 && t < T_) ? xsrc[c * T_ + t] : 0.f;
            xp[c * XROW + SWZ(jj)] = v;  // j>=384 overflow writes zeros onto zero-slots
        }
    }
    #pragma unroll
    for (int r = 0; r < 2; ++r) {
        int s = r * 64 + lane;
        float4 q = *(const float4*)(bary + ((size_t)kk * S_ + s) * C_ + cbase);
        bt[0 * BTROW + s] = q.x;
        bt[1 * BTROW + s] = q.y;
        bt[2 * BTROW + s] = q.z;
        bt[3 * BTROW + s] = q.w;
    }
    __syncthreads();

    int cl = lane >> 4;
    int gl = lane & 15;
    int lag0 = gl << 4;                  // 16 lags/lane
    const float* xr = xp + cl * XROW;
    const float* br = bt + cl * BTROW;

    float wdw[20];
    #pragma unroll
    for (int i = 0; i < 5; ++i) {
        float4 v = *(const float4*)&xr[SWZ(lag0 + 4 * i)];
        wdw[4*i+0] = v.x; wdw[4*i+1] = v.y; wdw[4*i+2] = v.z; wdw[4*i+3] = v.w;
    }
    float acc[16];
    #pragma unroll
    for (int jj = 0; jj < 16; ++jj) acc[jj] = 0.f;

    // 32 steps of 4 s-values; BASE cycles 0,4,8,12,16 with period 5.
    #pragma unroll 1
    for (int it = 0; it < 6; ++it) {
        int s4 = it * 20;
        cstep4<0 >(wdw, acc, br, xr, s4,      lag0);
        cstep4<4 >(wdw, acc, br, xr, s4 + 4,  lag0);
        cstep4<8 >(wdw, acc, br, xr, s4 + 8,  lag0);
        cstep4<12>(wdw, acc, br, xr, s4 + 12, lag0);
        cstep4<16>(wdw, acc, br, xr, s4 + 16, lag0);
    }
    cstep4<0>(wdw, acc, br, xr, 120, lag0);
    cstep4<4>(wdw, acc, br, xr, 124, lag0);

    if (gl == 15) acc[15] = -INF;        // lag 255 doesn't exist
    float m = acc[0];
    #pragma unroll
    for (int jj = 1; jj < 16; ++jj) m = fmaxf(m, acc[jj]);
    #pragma unroll
    for (int off = 8; off >= 1; off >>= 1)
        m = fmaxf(m, __shfl_xor(m, off));

    bool fail = false;
    if (gl == 0) fail = (m <= bottom_cc[kk * C_ + cbase + cl]);
    unsigned long long bal = __ballot(fail);
    if (lane == 0) cc_fail2[(b * K_ + kk) * 2 + h] = (bal != 0ULL) ? 1 : 0;
}

__global__ void final_kernel(const int* __restrict__ preds,
                             const int* __restrict__ dtw_gt,
                             const int* __restrict__ cc_fail2,
                             int* __restrict__ out) {
    int b = threadIdx.x;
    if (b < B_) {
        int dtw_all = 1, cc_all = 1;
        #pragma unroll
        for (int k = 0; k < K_; ++k) {
            dtw_all &= dtw_gt[b * K_ + k];
            cc_all &= (cc_fail2[(b * K_ + k) * 2] | cc_fail2[(b * K_ + k) * 2 + 1]);
        }
        out[b] = (dtw_all | cc_all) ? K_ : preds[b];
    }
}

extern "C" void kernel_launch(void* const* d_in, const int* in_sizes, int n_in,
                              void* d_out, int out_size, void* d_ws, size_t ws_size,
                              hipStream_t stream) {
    const float* x         = (const float*)d_in[0];  // [B, C, T]
    const int*   preds     = (const int*)d_in[1];    // [B]
    const float* bary      = (const float*)d_in[2];  // [K, S, C]
    const float* top_dist  = (const float*)d_in[3];  // [K]
    const float* bottom_cc = (const float*)d_in[4];  // [K, C]
    int* out = (int*)d_out;                          // [B] int32

    int* dtw_gt   = (int*)d_ws;                // [B*K]
    int* cc_fail2 = dtw_gt + B_ * K_;          // [B*K*2]

    dtw_kernel<<<320, 256, 0, stream>>>(x, bary, top_dist, dtw_gt);
    cc_kernel<<<1280, 256, 0, stream>>>(x, bary, bottom_cc, cc_fail2);
    final_kernel<<<1, 128, 0, stream>>>(preds, dtw_gt, cc_fail2, out);
}